// Round 3
// baseline (19402.362 us; speedup 1.0000x reference)
//
#include <hip/hip_runtime.h>
#include <cstdint>

#define NB 1024
#define NS 128
#define NE 256
#define NH 256

#define M_ENC 0
#define M_DEC0 1
#define M_DEC 2
#define M_QPROJ 3

typedef unsigned short ushort_t;

__device__ __forceinline__ void tf2x32(uint32_t k0, uint32_t k1, uint32_t x0, uint32_t x1,
                                       uint32_t &o0, uint32_t &o1) {
  const uint32_t ks2 = k0 ^ k1 ^ 0x1BD11BDAu;
#define TF_R(r) { x0 += x1; x1 = (x1 << (r)) | (x1 >> (32 - (r))); x1 ^= x0; }
  x0 += k0; x1 += k1;
  TF_R(13) TF_R(15) TF_R(26) TF_R(6)
  x0 += k1; x1 += ks2 + 1u;
  TF_R(17) TF_R(29) TF_R(16) TF_R(24)
  x0 += ks2; x1 += k0 + 2u;
  TF_R(13) TF_R(15) TF_R(26) TF_R(6)
  x0 += k0; x1 += k1 + 3u;
  TF_R(17) TF_R(29) TF_R(16) TF_R(24)
  x0 += k1; x1 += ks2 + 4u;
  TF_R(13) TF_R(15) TF_R(26) TF_R(6)
  x0 += ks2; x1 += k0 + 5u;
#undef TF_R
  o0 = x0; o1 = x1;
}

__device__ __forceinline__ float fast_tanh(float x) {
  float ax = fabsf(x);
  float e = __expf(2.0f * ax);
  float r = 1.0f - 2.0f / (e + 1.0f);
  return copysignf(r, x);
}

__device__ __forceinline__ float sigm(float x) { return 1.0f / (1.0f + expf(-x)); }

// ---- 3.5-byte key codec: bf16-hi + 12-bit lo (keeps fp32 bits [31:4], RTN) ----
__device__ __forceinline__ void pack12(float4 o, ushort4 &hi, ushort_t &u0, ushort_t &u1, ushort_t &u2) {
  uint32_t a = __float_as_uint(o.x) + 8u;
  uint32_t b = __float_as_uint(o.y) + 8u;
  uint32_t c = __float_as_uint(o.z) + 8u;
  uint32_t d = __float_as_uint(o.w) + 8u;
  hi = make_ushort4((ushort_t)(a >> 16), (ushort_t)(b >> 16), (ushort_t)(c >> 16), (ushort_t)(d >> 16));
  uint32_t l0 = (a >> 4) & 0xFFFu, l1 = (b >> 4) & 0xFFFu, l2 = (c >> 4) & 0xFFFu, l3 = (d >> 4) & 0xFFFu;
  u0 = (ushort_t)(l0 | (l1 << 12));
  u1 = (ushort_t)((l1 >> 4) | (l2 << 8));
  u2 = (ushort_t)((l2 >> 8) | (l3 << 4));
}

__device__ __forceinline__ float4 unpack12(ushort4 h, ushort_t u0, ushort_t u1, ushort_t u2) {
  uint32_t l0 = u0 & 0xFFFu;
  uint32_t l1 = ((u0 >> 12) | ((uint32_t)u1 << 4)) & 0xFFFu;
  uint32_t l2 = ((u1 >> 8) | ((uint32_t)u2 << 8)) & 0xFFFu;
  uint32_t l3 = ((uint32_t)u2 >> 4) & 0xFFFu;
  float4 r;
  r.x = __uint_as_float(((uint32_t)h.x << 16) | (l0 << 4));
  r.y = __uint_as_float(((uint32_t)h.y << 16) | (l1 << 4));
  r.z = __uint_as_float(((uint32_t)h.z << 16) | (l2 << 4));
  r.w = __uint_as_float(((uint32_t)h.w << 16) | (l3 << 4));
  return r;
}

// keys for slot s, lane-column h0 (h0 = lane*4): fp32 if s < nf, else hi+lo12
__device__ __forceinline__ float4 key_load(const float* kf, const ushort_t* kh, const ushort_t* kl,
                                           size_t bf, size_t bq, int s, int nf, int h0) {
  if (s < nf) {
    return *(const float4*)(kf + bf + (size_t)s * 256 + h0);
  } else {
    size_t qb = bq + (size_t)(s - nf);
    ushort4 hv = *(const ushort4*)(kh + qb * 256 + h0);
    const ushort_t* lp = kl + qb * 192 + 3 * (h0 >> 2);
    return unpack12(hv, lp[0], lp[1], lp[2]);
  }
}

// ---------------- prep: fold emb_W through input weights; threefry split keys ----------------
__global__ __launch_bounds__(256) void prep_kernel(
    const float* __restrict__ emb_W, const float* __restrict__ enc_W_ih,
    const float* __restrict__ dec_W_ih, const float* __restrict__ dec_start,
    float* __restrict__ F_enc, float* __restrict__ F_dec,
    float* __restrict__ d0proj, uint2* __restrict__ skeys) {
  int j = blockIdx.x * 256 + threadIdx.x;  // 0..1023
  const float* er = enc_W_ih + j * 256;
  const float* dr = dec_W_ih + j * 256;
  float fe0 = 0.f, fe1 = 0.f, fd0 = 0.f, fd1 = 0.f, dp = 0.f;
  for (int e = 0; e < 256; ++e) {
    float we0 = emb_W[e], we1 = emb_W[256 + e];
    float ev = er[e], dv = dr[e];
    fe0 = fmaf(we0, ev, fe0); fe1 = fmaf(we1, ev, fe1);
    fd0 = fmaf(we0, dv, fd0); fd1 = fmaf(we1, dv, fd1);
    dp = fmaf(dec_start[e], dv, dp);
  }
  F_enc[j] = fe0; F_enc[1024 + j] = fe1;
  F_dec[j] = fd0; F_dec[1024 + j] = fd1;
  d0proj[j] = dp;
  if (blockIdx.x == 0 && threadIdx.x < NS) {
    uint32_t o0, o1;
    tf2x32(0u, 42u, 0u, (uint32_t)threadIdx.x, o0, o1);
    skeys[threadIdx.x] = make_uint2(o0, o1);
  }
}

__global__ void diag_fill(float* out, float v, int n) {
  int i = blockIdx.x * blockDim.x + threadIdx.x;
  if (i < n) out[i] = v;
}

// ---------------- GEMM macro body (64x64 tile, K=256) ----------------
#define GEMM_LOAD_COMPUTE()                                                         \
  float acc[4][4];                                                                  \
  _Pragma("unroll") for (int i = 0; i < 4; ++i)                                     \
      _Pragma("unroll") for (int j = 0; j < 4; ++j) acc[i][j] = 0.0f;               \
  for (int k0 = 0; k0 < 256; k0 += 32) {                                            \
    float4 a0 = *(const float4*)(ap0 + k0);                                         \
    float4 a1 = *(const float4*)(ap1 + k0);                                         \
    float4 b0 = *(const float4*)(brow0 + k0);                                       \
    float4 b1 = *(const float4*)(brow1 + k0);                                       \
    __syncthreads();                                                                \
    As[(c4 + 0) * 68 + nl0] = a0.x; As[(c4 + 1) * 68 + nl0] = a0.y;                 \
    As[(c4 + 2) * 68 + nl0] = a0.z; As[(c4 + 3) * 68 + nl0] = a0.w;                 \
    As[(c4 + 0) * 68 + nl1] = a1.x; As[(c4 + 1) * 68 + nl1] = a1.y;                 \
    As[(c4 + 2) * 68 + nl1] = a1.z; As[(c4 + 3) * 68 + nl1] = a1.w;                 \
    Bs[(c4 + 0) * 68 + nl0] = b0.x; Bs[(c4 + 1) * 68 + nl0] = b0.y;                 \
    Bs[(c4 + 2) * 68 + nl0] = b0.z; Bs[(c4 + 3) * 68 + nl0] = b0.w;                 \
    Bs[(c4 + 0) * 68 + nl1] = b1.x; Bs[(c4 + 1) * 68 + nl1] = b1.y;                 \
    Bs[(c4 + 2) * 68 + nl1] = b1.z; Bs[(c4 + 3) * 68 + nl1] = b1.w;                 \
    __syncthreads();                                                                \
    _Pragma("unroll") for (int kk = 0; kk < 32; ++kk) {                             \
      float4 av = *(const float4*)(As + kk * 68 + ty * 4);                          \
      float4 bv = *(const float4*)(Bs + kk * 68 + tx * 4);                          \
      acc[0][0] = fmaf(av.x, bv.x, acc[0][0]);                                      \
      acc[0][1] = fmaf(av.x, bv.y, acc[0][1]);                                      \
      acc[0][2] = fmaf(av.x, bv.z, acc[0][2]);                                      \
      acc[0][3] = fmaf(av.x, bv.w, acc[0][3]);                                      \
      acc[1][0] = fmaf(av.y, bv.x, acc[1][0]);                                      \
      acc[1][1] = fmaf(av.y, bv.y, acc[1][1]);                                      \
      acc[1][2] = fmaf(av.y, bv.z, acc[1][2]);                                      \
      acc[1][3] = fmaf(av.y, bv.w, acc[1][3]);                                      \
      acc[2][0] = fmaf(av.z, bv.x, acc[2][0]);                                      \
      acc[2][1] = fmaf(av.z, bv.y, acc[2][1]);                                      \
      acc[2][2] = fmaf(av.z, bv.z, acc[2][2]);                                      \
      acc[2][3] = fmaf(av.z, bv.w, acc[2][3]);                                      \
      acc[3][0] = fmaf(av.w, bv.x, acc[3][0]);                                      \
      acc[3][1] = fmaf(av.w, bv.y, acc[3][1]);                                      \
      acc[3][2] = fmaf(av.w, bv.z, acc[3][2]);                                      \
      acc[3][3] = fmaf(av.w, bv.w, acc[3][3]);                                      \
    }                                                                               \
  }

// ---------------- LSTM / QPROJ GEMM ----------------
template <int MODE>
__global__ __launch_bounds__(256) void gemm_kernel(
    const float* __restrict__ A, const float* __restrict__ B0,
    const float* __restrict__ bias0, const float* __restrict__ bias1,
    float* __restrict__ out0, float* __restrict__ out1,
    const float* __restrict__ x, const float* __restrict__ F,
    const int* __restrict__ chosen, int t) {
  __shared__ float smem[64 * 68];
  float* As = smem;
  float* Bs = smem + 32 * 68;
  const int tid = threadIdx.x;
  const int tx = tid & 15, ty = tid >> 4;
  const int m0 = blockIdx.x * 64;
  const int nl0 = tid >> 3, nl1 = nl0 + 32;
  const int c4 = (tid & 7) * 4;

  int j0, j1;
  if constexpr (MODE != M_QPROJ) {
    j0 = ((nl0 >> 4) << 8) + (blockIdx.y << 4) + (nl0 & 15);
    j1 = ((nl1 >> 4) << 8) + (blockIdx.y << 4) + (nl1 & 15);
  } else {
    j0 = blockIdx.y * 64 + nl0;
    j1 = blockIdx.y * 64 + nl1;
  }
  const float* brow0 = B0 + j0 * 256 + c4;
  const float* brow1 = B0 + j1 * 256 + c4;
  const float* ap0 = A + (size_t)(m0 + nl0) * 256 + c4;
  const float* ap1 = A + (size_t)(m0 + nl1) * 256 + c4;

  GEMM_LOAD_COMPUTE()

  if constexpr (MODE == M_QPROJ) {
    const int nbase = blockIdx.y * 64 + tx * 4;
    float4 b4 = *(const float4*)(bias0 + nbase);
#pragma unroll
    for (int r = 0; r < 4; ++r) {
      int m = m0 + ty * 4 + r;
      float4 o;
      o.x = acc[r][0] + b4.x; o.y = acc[r][1] + b4.y;
      o.z = acc[r][2] + b4.z; o.w = acc[r][3] + b4.w;
      *(float4*)(out0 + (size_t)m * 256 + nbase) = o;
    }
  } else {
    float bsum[4], fa[4], fb[4];
#pragma unroll
    for (int c = 0; c < 4; ++c) {
      int n = tx * 4 + c;
      int j = ((n >> 4) << 8) + (blockIdx.y << 4) + (n & 15);
      bsum[c] = bias0[j] + bias1[j];
      fa[c] = F[j];
      if constexpr (MODE != M_DEC0) fb[c] = F[1024 + j]; else fb[c] = 0.0f;
    }
    float xv0[4] = {0, 0, 0, 0}, xv1[4] = {0, 0, 0, 0};
    if constexpr (MODE == M_ENC) {
#pragma unroll
      for (int r = 0; r < 4; ++r) {
        int m = m0 + ty * 4 + r;
        xv0[r] = x[m * (NS * 2) + t * 2 + 0];
        xv1[r] = x[m * (NS * 2) + t * 2 + 1];
      }
    } else if constexpr (MODE == M_DEC) {
#pragma unroll
      for (int r = 0; r < 4; ++r) {
        int m = m0 + ty * 4 + r;
        int cs = chosen[m];
        xv0[r] = x[m * (NS * 2) + cs * 2 + 0];
        xv1[r] = x[m * (NS * 2) + cs * 2 + 1];
      }
    }
    __syncthreads();
    float* Cs = smem;
#pragma unroll
    for (int r = 0; r < 4; ++r) {
#pragma unroll
      for (int c = 0; c < 4; ++c) {
        float v = acc[r][c] + bsum[c];
        if constexpr (MODE == M_DEC0) v += fa[c];
        else v += xv0[r] * fa[c] + xv1[r] * fb[c];
        Cs[(ty * 4 + r) * 68 + tx * 4 + c] = v;
      }
    }
    __syncthreads();
    const int b_l = tid >> 2;
    const int h4 = (tid & 3) * 4;
    const float* crow = Cs + b_l * 68;
    float4 gi = *(const float4*)(crow + h4);
    float4 gf = *(const float4*)(crow + 16 + h4);
    float4 gg = *(const float4*)(crow + 32 + h4);
    float4 go = *(const float4*)(crow + 48 + h4);
    size_t base = (size_t)(m0 + b_l) * 256 + (blockIdx.y << 4) + h4;
    float4 cp = *(const float4*)(out1 + base);
    float4 cn, hn;
    cn.x = sigm(gf.x) * cp.x + sigm(gi.x) * tanhf(gg.x); hn.x = sigm(go.x) * tanhf(cn.x);
    cn.y = sigm(gf.y) * cp.y + sigm(gi.y) * tanhf(gg.y); hn.y = sigm(go.y) * tanhf(cn.y);
    cn.z = sigm(gf.z) * cp.z + sigm(gi.z) * tanhf(gg.z); hn.z = sigm(go.z) * tanhf(cn.z);
    cn.w = sigm(gf.w) * cp.w + sigm(gi.w) * tanhf(gg.w); hn.w = sigm(go.w) * tanhf(cn.w);
    *(float4*)(out1 + base) = cn;
    *(float4*)(out0 + base) = hn;
  }
}

// ---------------- keys GEMM: [g_Wk ; p_Wk] applied to h_t, per-slot precision stores ----------------
__global__ __launch_bounds__(256) void keys_kernel(
    const float* __restrict__ A, const float* __restrict__ gW, const float* __restrict__ pW,
    const float* __restrict__ gB, const float* __restrict__ pB,
    float* gkf, ushort_t* gkh, ushort_t* gkl,
    float* pkf, ushort_t* pkh, ushort_t* pkl,
    int t, int nfg, int nqg, int nfp, int nqp) {
  __shared__ float smem[64 * 68];
  float* As = smem;
  float* Bs = smem + 32 * 68;
  const int tid = threadIdx.x;
  const int tx = tid & 15, ty = tid >> 4;
  const int m0 = blockIdx.x * 64;
  const int nl0 = tid >> 3, nl1 = nl0 + 32;
  const int c4 = (tid & 7) * 4;

  const int j0 = blockIdx.y * 64 + nl0;
  const int j1 = blockIdx.y * 64 + nl1;
  const float* brow0 = ((j0 < 256) ? (gW + j0 * 256) : (pW + (j0 - 256) * 256)) + c4;
  const float* brow1 = ((j1 < 256) ? (gW + j1 * 256) : (pW + (j1 - 256) * 256)) + c4;
  const float* ap0 = A + (size_t)(m0 + nl0) * 256 + c4;
  const float* ap1 = A + (size_t)(m0 + nl1) * 256 + c4;

  GEMM_LOAD_COMPUTE()

  const int nbase = blockIdx.y * 64 + tx * 4;
  const bool isp = (nbase >= 256);
  const int n = isp ? (nbase - 256) : nbase;
  float4 b4 = *(const float4*)((isp ? pB : gB) + n);
  float* kf = isp ? pkf : gkf;
  ushort_t* kh = isp ? pkh : gkh;
  ushort_t* kl = isp ? pkl : gkl;
  const int nf = isp ? nfp : nfg;
  const int nq = isp ? nqp : nqg;
#pragma unroll
  for (int r = 0; r < 4; ++r) {
    int m = m0 + ty * 4 + r;
    float4 o;
    o.x = acc[r][0] + b4.x; o.y = acc[r][1] + b4.y;
    o.z = acc[r][2] + b4.z; o.w = acc[r][3] + b4.w;
    if (t < nf) {
      *(float4*)(kf + ((size_t)m * nf + t) * 256 + n) = o;
    } else {
      size_t qb = (size_t)m * nq + (t - nf);
      ushort4 hi; ushort_t u0, u1, u2;
      pack12(o, hi, u0, u1, u2);
      *(ushort4*)(kh + qb * 256 + n) = hi;
      ushort_t* lp = kl + qb * 192 + 3 * (n >> 2);
      lp[0] = u0; lp[1] = u1; lp[2] = u2;
    }
  }
}

// ---------------- glimpse: single-pass online-softmax attention ----------------
__global__ __launch_bounds__(256) void glimpse_kernel(
    const float* __restrict__ q, const float* kf, const ushort_t* kh, const ushort_t* kl,
    int nf, int nq, const float* __restrict__ vw, const float* __restrict__ vb,
    const int* __restrict__ mask, float* __restrict__ query) {
  __shared__ float qs[256], vs[256];
  __shared__ float wm[4], wl[4], part[4][256];
  __shared__ int msk[NS];
  const int tid = threadIdx.x;
  const int b = blockIdx.x;
  const int wave = tid >> 6, lane = tid & 63;
  qs[tid] = q[b * 256 + tid];
  vs[tid] = vw[tid];
  if (tid < NS) msk[tid] = mask[b * NS + tid];
  __syncthreads();
  const size_t bf = (size_t)b * nf * 256;
  const size_t bq = (size_t)b * nq;
  const float vbias = vb[0];
  const int h0 = lane * 4;
  float q0 = qs[h0], q1 = qs[h0 + 1], q2 = qs[h0 + 2], q3 = qs[h0 + 3];
  float v0 = vs[h0], v1 = vs[h0 + 1], v2 = vs[h0 + 2], v3 = vs[h0 + 3];
  float m = -INFINITY, l = 0.f;
  float4 acc = make_float4(0.f, 0.f, 0.f, 0.f);
  for (int si = 0; si < 32; ++si) {
    int s = wave * 32 + si;
    float4 kv = key_load(kf, kh, kl, bf, bq, s, nf, h0);
    float p = fast_tanh(q0 + kv.x) * v0 + fast_tanh(q1 + kv.y) * v1 +
              fast_tanh(q2 + kv.z) * v2 + fast_tanh(q3 + kv.w) * v3;
#pragma unroll
    for (int off = 32; off; off >>= 1) p += __shfl_xor(p, off);
    if (!msk[s]) {
      float lg = 10.0f * tanhf(p + vbias);
      float mn = fmaxf(m, lg);
      float scale = (m == -INFINITY) ? 0.0f : expf(m - mn);
      float pe = expf(lg - mn);
      acc.x = fmaf(acc.x, scale, pe * kv.x);
      acc.y = fmaf(acc.y, scale, pe * kv.y);
      acc.z = fmaf(acc.z, scale, pe * kv.z);
      acc.w = fmaf(acc.w, scale, pe * kv.w);
      l = l * scale + pe;
      m = mn;
    }
  }
  *(float4*)&part[wave][h0] = acc;
  if (lane == 0) { wm[wave] = m; wl[wave] = l; }
  __syncthreads();
  float mg = fmaxf(fmaxf(wm[0], wm[1]), fmaxf(wm[2], wm[3]));
  float w0 = (wm[0] == -INFINITY) ? 0.f : expf(wm[0] - mg);
  float w1 = (wm[1] == -INFINITY) ? 0.f : expf(wm[1] - mg);
  float w2 = (wm[2] == -INFINITY) ? 0.f : expf(wm[2] - mg);
  float w3 = (wm[3] == -INFINITY) ? 0.f : expf(wm[3] - mg);
  float denom = w0 * wl[0] + w1 * wl[1] + w2 * wl[2] + w3 * wl[3];
  float num = w0 * part[0][tid] + w1 * part[1][tid] + w2 * part[2][tid] + w3 * part[3][tid];
  query[b * 256 + tid] = num / denom;
}

// ---------------- pointer attention + log_softmax + gumbel categorical sample ----------------
__global__ __launch_bounds__(256) void pointer_kernel(
    const float* __restrict__ q, const float* kf, const ushort_t* kh, const ushort_t* kl,
    int nf, int nq, const float* __restrict__ vw, const float* __restrict__ vb,
    int* __restrict__ mask, const uint2* __restrict__ skeys, int t,
    float* __restrict__ out, int* __restrict__ chosen_buf) {
  __shared__ float qs[256], vs[256], lg[NS], sv[NS];
  __shared__ int msk[NS];
  __shared__ float red_lse;
  __shared__ int ich;
  const int tid = threadIdx.x;
  const int b = blockIdx.x;
  const int wave = tid >> 6, lane = tid & 63;
  qs[tid] = q[b * 256 + tid];
  vs[tid] = vw[tid];
  if (tid < NS) msk[tid] = mask[b * NS + tid];
  __syncthreads();
  const size_t bf = (size_t)b * nf * 256;
  const size_t bq = (size_t)b * nq;
  const float vbias = vb[0];
  const int h0 = lane * 4;
  float q0 = qs[h0], q1 = qs[h0 + 1], q2 = qs[h0 + 2], q3 = qs[h0 + 3];
  float v0 = vs[h0], v1 = vs[h0 + 1], v2 = vs[h0 + 2], v3 = vs[h0 + 3];
  for (int si = 0; si < 32; ++si) {
    int s = wave * 32 + si;
    float4 kv = key_load(kf, kh, kl, bf, bq, s, nf, h0);
    float p = fast_tanh(q0 + kv.x) * v0 + fast_tanh(q1 + kv.y) * v1 +
              fast_tanh(q2 + kv.z) * v2 + fast_tanh(q3 + kv.w) * v3;
#pragma unroll
    for (int off = 32; off; off >>= 1) p += __shfl_down(p, off);
    if (lane == 0) {
      float lv = 10.0f * tanhf(p + vbias);
      lg[s] = msk[s] ? -100000.0f : lv;
    }
  }
  __syncthreads();
  if (wave == 0) {
    float a0 = lg[lane], a1 = lg[lane + 64];
    float m = fmaxf(a0, a1);
#pragma unroll
    for (int off = 32; off; off >>= 1) m = fmaxf(m, __shfl_xor(m, off));
    float e0 = expf(a0 - m), e1 = expf(a1 - m);
    float sum = e0 + e1;
#pragma unroll
    for (int off = 32; off; off >>= 1) sum += __shfl_xor(sum, off);
    if (lane == 0) red_lse = m + logf(sum);
  }
  __syncthreads();
  if (tid < NS) {
    // JAX threefry_partitionable 32-bit bits: o0 ^ o1 of threefry(key, (0, i))
    uint32_t i = (uint32_t)(b * NS + tid);
    uint2 sk = skeys[t];
    uint32_t o0, o1;
    tf2x32(sk.x, sk.y, 0u, i, o0, o1);
    uint32_t bits = o0 ^ o1;
    float u = __uint_as_float((bits >> 9) | 0x3f800000u) - 1.0f;
    u = u + 1.17549435e-38f;
    u = fmaxf(u, 1.17549435e-38f);
    float g = -logf(-logf(u));
    sv[tid] = lg[tid] + g;
  }
  __syncthreads();
  if (wave == 0) {
    float bv = sv[lane]; int bi = lane;
    float ov0 = sv[lane + 64];
    if (ov0 > bv) { bv = ov0; bi = lane + 64; }
#pragma unroll
    for (int off = 32; off; off >>= 1) {
      float ov = __shfl_down(bv, off);
      int oi = __shfl_down(bi, off);
      if (ov > bv) { bv = ov; bi = oi; }
    }
    if (lane == 0) ich = bi;
  }
  __syncthreads();
  if (tid == 0) {
    int cs = ich;
    out[b * NS + t] = lg[cs] - red_lse;
    out[NB * NS + b * NS + t] = (float)cs;
    mask[b * NS + cs] = 1;
    chosen_buf[b] = cs;
  }
}

extern "C" void kernel_launch(void* const* d_in, const int* in_sizes, int n_in,
                              void* d_out, int out_size, void* d_ws, size_t ws_size,
                              hipStream_t stream) {
  const float* x        = (const float*)d_in[0];
  const float* emb_W    = (const float*)d_in[1];
  const float* enc_W_ih = (const float*)d_in[2];
  const float* enc_W_hh = (const float*)d_in[3];
  const float* enc_b_ih = (const float*)d_in[4];
  const float* enc_b_hh = (const float*)d_in[5];
  const float* dec_W_ih = (const float*)d_in[6];
  const float* dec_W_hh = (const float*)d_in[7];
  const float* dec_b_ih = (const float*)d_in[8];
  const float* dec_b_hh = (const float*)d_in[9];
  const float* g_Wq_w = (const float*)d_in[10];
  const float* g_Wq_b = (const float*)d_in[11];
  const float* g_Wk_w = (const float*)d_in[12];
  const float* g_Wk_b = (const float*)d_in[13];
  const float* g_v_w  = (const float*)d_in[14];
  const float* g_v_b  = (const float*)d_in[15];
  const float* p_Wq_w = (const float*)d_in[16];
  const float* p_Wq_b = (const float*)d_in[17];
  const float* p_Wk_w = (const float*)d_in[18];
  const float* p_Wk_b = (const float*)d_in[19];
  const float* p_v_w  = (const float*)d_in[20];
  const float* p_v_b  = (const float*)d_in[21];
  const float* dec_start = (const float*)d_in[22];
  (void)in_sizes; (void)n_in;

  // ---- per-slot key precision plan: fp32 slots + 3.5-byte (bf16+12lo) tail slots ----
  // Full fp32 both heads = 256 MiB. Each quantized slot saves 131072 B.
  const size_t SLOT_F = (size_t)NB * NH * 4;                 // 1 MiB per slot
  const size_t SLOT_H = (size_t)NB * NH * 2;                 // hi 512 KiB
  const size_t SLOT_L = (size_t)NB * 192 * 2;                // lo12 384 KiB
  const size_t FULLK = 256 * SLOT_F;                         // both heads, all fp32
  const size_t EX = 5 * 1048576 + 524288 + 4096 + 8192 + 8192 + 4096 + 1024 + 8192;
  long long deficit = (long long)(FULLK + EX) - (long long)ws_size;
  int nq_total = (deficit <= 0) ? 0 : (int)((deficit + 131071) / 131072);
  if (nq_total > 256) {
    diag_fill<<<(out_size + 255) / 256, 256, 0, stream>>>((float*)d_out, (float)ws_size, out_size);
    return;
  }
  const int nq_p = nq_total < 128 ? nq_total : 128;   // quantize pointer tail first
  const int nq_g = nq_total - nq_p;
  const int nf_p = 128 - nq_p;
  const int nf_g = 128 - nq_g;

  char* w = (char*)d_ws;
  size_t off = 0;
  auto alloc = [&](size_t bytes) -> void* {
    void* p = w + off;
    off += (bytes + 255) & ~(size_t)255;
    return p;
  };
  float*    gkf = (float*)alloc((size_t)nf_g * SLOT_F);
  ushort_t* gkh = (ushort_t*)alloc((size_t)nq_g * SLOT_H);
  ushort_t* gkl = (ushort_t*)alloc((size_t)nq_g * SLOT_L);
  float*    pkf = (float*)alloc((size_t)nf_p * SLOT_F);
  ushort_t* pkh = (ushort_t*)alloc((size_t)nq_p * SLOT_H);
  ushort_t* pkl = (ushort_t*)alloc((size_t)nq_p * SLOT_L);

  float* h0buf  = (float*)alloc((size_t)NB * NH * 4);
  float* h1buf  = (float*)alloc((size_t)NB * NH * 4);
  float* cbuf   = (float*)alloc((size_t)NB * NH * 4);
  float* qg     = (float*)alloc((size_t)NB * NH * 4);   // also reused as qp
  float* query  = (float*)alloc((size_t)NB * NH * 4);
  int*   mask   = (int*)alloc((size_t)NB * NS * 4);
  int*   chosen = (int*)alloc((size_t)NB * 4);
  float* F_enc  = (float*)alloc(2048 * 4);
  float* F_dec  = (float*)alloc(2048 * 4);
  float* d0proj = (float*)alloc(1024 * 4);
  uint2* skeys  = (uint2*)alloc(NS * 8);
  float* qp = qg;  // alias: qg dead once glimpse has read it

  if (off > ws_size) {
    diag_fill<<<(out_size + 255) / 256, 256, 0, stream>>>((float*)d_out, (float)ws_size, out_size);
    return;
  }

  hipMemsetAsync(h0buf, 0, (size_t)NB * NH * 4, stream);
  hipMemsetAsync(cbuf, 0, (size_t)NB * NH * 4, stream);
  hipMemsetAsync(mask, 0, (size_t)NB * NS * 4, stream);
  prep_kernel<<<4, 256, 0, stream>>>(emb_W, enc_W_ih, dec_W_ih, dec_start,
                                     F_enc, F_dec, d0proj, skeys);

  float* hbuf[2] = {h0buf, h1buf};
  // ---- encoder ----
  for (int t = 0; t < NS; ++t) {
    gemm_kernel<M_ENC><<<dim3(16, 16), 256, 0, stream>>>(
        hbuf[t & 1], enc_W_hh, enc_b_ih, enc_b_hh,
        hbuf[(t + 1) & 1], cbuf, x, F_enc, nullptr, t);
    keys_kernel<<<dim3(16, 8), 256, 0, stream>>>(
        hbuf[(t + 1) & 1], g_Wk_w, p_Wk_w, g_Wk_b, p_Wk_b,
        gkf, gkh, gkl, pkf, pkh, pkl, t, nf_g, nq_g, nf_p, nq_p);
  }
  // ---- decoder ----
  for (int t = 0; t < NS; ++t) {
    if (t == 0) {
      gemm_kernel<M_DEC0><<<dim3(16, 16), 256, 0, stream>>>(
          hbuf[0], dec_W_hh, dec_b_ih, dec_b_hh,
          hbuf[1], cbuf, nullptr, d0proj, nullptr, t);
    } else {
      gemm_kernel<M_DEC><<<dim3(16, 16), 256, 0, stream>>>(
          hbuf[t & 1], dec_W_hh, dec_b_ih, dec_b_hh,
          hbuf[(t + 1) & 1], cbuf, x, F_dec, chosen, t);
    }
    float* hcur = hbuf[(t + 1) & 1];
    gemm_kernel<M_QPROJ><<<dim3(16, 4), 256, 0, stream>>>(
        hcur, g_Wq_w, g_Wq_b, nullptr, qg, nullptr, nullptr, nullptr, nullptr, t);
    glimpse_kernel<<<NB, 256, 0, stream>>>(qg, gkf, gkh, gkl, nf_g, nq_g,
                                           g_v_w, g_v_b, mask, query);
    gemm_kernel<M_QPROJ><<<dim3(16, 4), 256, 0, stream>>>(
        query, p_Wq_w, p_Wq_b, nullptr, qp, nullptr, nullptr, nullptr, nullptr, t);
    pointer_kernel<<<NB, 256, 0, stream>>>(qp, pkf, pkh, pkl, nf_p, nq_p,
                                           p_v_w, p_v_b, mask, skeys, t,
                                           (float*)d_out, chosen);
  }
}

// Round 4
// 16626.288 us; speedup vs baseline: 1.1670x; 1.1670x over previous
//
#include <hip/hip_runtime.h>
#include <cstdint>

#define NB 1024
#define NS 128
#define NE 256
#define NH 256

#define M_ENC 0
#define M_DEC0 1
#define M_DEC 2

typedef unsigned short ushort_t;

__device__ __forceinline__ void tf2x32(uint32_t k0, uint32_t k1, uint32_t x0, uint32_t x1,
                                       uint32_t &o0, uint32_t &o1) {
  const uint32_t ks2 = k0 ^ k1 ^ 0x1BD11BDAu;
#define TF_R(r) { x0 += x1; x1 = (x1 << (r)) | (x1 >> (32 - (r))); x1 ^= x0; }
  x0 += k0; x1 += k1;
  TF_R(13) TF_R(15) TF_R(26) TF_R(6)
  x0 += k1; x1 += ks2 + 1u;
  TF_R(17) TF_R(29) TF_R(16) TF_R(24)
  x0 += ks2; x1 += k0 + 2u;
  TF_R(13) TF_R(15) TF_R(26) TF_R(6)
  x0 += k0; x1 += k1 + 3u;
  TF_R(17) TF_R(29) TF_R(16) TF_R(24)
  x0 += k1; x1 += ks2 + 4u;
  TF_R(13) TF_R(15) TF_R(26) TF_R(6)
  x0 += ks2; x1 += k0 + 5u;
#undef TF_R
  o0 = x0; o1 = x1;
}

__device__ __forceinline__ float fast_tanh(float x) {
  float ax = fabsf(x);
  float e = __expf(2.0f * ax);
  float r = 1.0f - 2.0f / (e + 1.0f);
  return copysignf(r, x);
}

__device__ __forceinline__ float sigm(float x) { return 1.0f / (1.0f + expf(-x)); }

// ---- 3.5-byte key codec: bf16-hi + 12-bit lo (keeps fp32 bits [31:4], RTN) ----
__device__ __forceinline__ void pack12(float4 o, ushort4 &hi, ushort_t &u0, ushort_t &u1, ushort_t &u2) {
  uint32_t a = __float_as_uint(o.x) + 8u;
  uint32_t b = __float_as_uint(o.y) + 8u;
  uint32_t c = __float_as_uint(o.z) + 8u;
  uint32_t d = __float_as_uint(o.w) + 8u;
  hi = make_ushort4((ushort_t)(a >> 16), (ushort_t)(b >> 16), (ushort_t)(c >> 16), (ushort_t)(d >> 16));
  uint32_t l0 = (a >> 4) & 0xFFFu, l1 = (b >> 4) & 0xFFFu, l2 = (c >> 4) & 0xFFFu, l3 = (d >> 4) & 0xFFFu;
  u0 = (ushort_t)(l0 | (l1 << 12));
  u1 = (ushort_t)((l1 >> 4) | (l2 << 8));
  u2 = (ushort_t)((l2 >> 8) | (l3 << 4));
}

__device__ __forceinline__ float4 unpack12(ushort4 h, ushort_t u0, ushort_t u1, ushort_t u2) {
  uint32_t l0 = u0 & 0xFFFu;
  uint32_t l1 = ((u0 >> 12) | ((uint32_t)u1 << 4)) & 0xFFFu;
  uint32_t l2 = ((u1 >> 8) | ((uint32_t)u2 << 8)) & 0xFFFu;
  uint32_t l3 = ((uint32_t)u2 >> 4) & 0xFFFu;
  float4 r;
  r.x = __uint_as_float(((uint32_t)h.x << 16) | (l0 << 4));
  r.y = __uint_as_float(((uint32_t)h.y << 16) | (l1 << 4));
  r.z = __uint_as_float(((uint32_t)h.z << 16) | (l2 << 4));
  r.w = __uint_as_float(((uint32_t)h.w << 16) | (l3 << 4));
  return r;
}

__device__ __forceinline__ float4 key_load(const float* kf, const ushort_t* kh, const ushort_t* kl,
                                           size_t bf, size_t bq, int s, int nf, int h0) {
  if (s < nf) {
    return *(const float4*)(kf + bf + (size_t)s * 256 + h0);
  } else {
    size_t qb = bq + (size_t)(s - nf);
    ushort4 hv = *(const ushort4*)(kh + qb * 256 + h0);
    const ushort_t* lp = kl + qb * 192 + 3 * (h0 >> 2);
    return unpack12(hv, lp[0], lp[1], lp[2]);
  }
}

// ---------------- prep: fold emb_W through input weights; threefry split keys ----------------
__global__ __launch_bounds__(256) void prep_kernel(
    const float* __restrict__ emb_W, const float* __restrict__ enc_W_ih,
    const float* __restrict__ dec_W_ih, const float* __restrict__ dec_start,
    float* __restrict__ F_enc, float* __restrict__ F_dec,
    float* __restrict__ d0proj, uint2* __restrict__ skeys) {
  int j = blockIdx.x * 256 + threadIdx.x;  // 0..1023
  const float* er = enc_W_ih + j * 256;
  const float* dr = dec_W_ih + j * 256;
  float fe0 = 0.f, fe1 = 0.f, fd0 = 0.f, fd1 = 0.f, dp = 0.f;
  for (int e = 0; e < 256; ++e) {
    float we0 = emb_W[e], we1 = emb_W[256 + e];
    float ev = er[e], dv = dr[e];
    fe0 = fmaf(we0, ev, fe0); fe1 = fmaf(we1, ev, fe1);
    fd0 = fmaf(we0, dv, fd0); fd1 = fmaf(we1, dv, fd1);
    dp = fmaf(dec_start[e], dv, dp);
  }
  F_enc[j] = fe0; F_enc[1024 + j] = fe1;
  F_dec[j] = fd0; F_dec[1024 + j] = fd1;
  d0proj[j] = dp;
  if (blockIdx.x == 0 && threadIdx.x < NS) {
    uint32_t o0, o1;
    tf2x32(0u, 42u, 0u, (uint32_t)threadIdx.x, o0, o1);
    skeys[threadIdx.x] = make_uint2(o0, o1);
  }
}

// transpose the two query-projection weights: WT[k][j] = W[j][k]
__global__ __launch_bounds__(256) void transpose_qw(
    const float* __restrict__ gW, const float* __restrict__ pW,
    float* __restrict__ gWT, float* __restrict__ pWT) {
  int k = blockIdx.x, j = threadIdx.x;
  gWT[k * 256 + j] = gW[j * 256 + k];
  pWT[k * 256 + j] = pW[j * 256 + k];
}

__global__ void diag_fill(float* out, float v, int n) {
  int i = blockIdx.x * blockDim.x + threadIdx.x;
  if (i < n) out[i] = v;
}

// ---------------- GEMM macro body: 512 threads, 64x64 tile, K=256, acc[2][4] ----------------
#define GEMM_LOAD_COMPUTE()                                                         \
  float acc[2][4];                                                                  \
  _Pragma("unroll") for (int i = 0; i < 2; ++i)                                     \
      _Pragma("unroll") for (int jj = 0; jj < 4; ++jj) acc[i][jj] = 0.0f;           \
  for (int k0 = 0; k0 < 256; k0 += 32) {                                            \
    float4 a0 = *(const float4*)(ap + k0);                                          \
    float4 b0 = *(const float4*)(brow + k0);                                        \
    __syncthreads();                                                                \
    As[(c4 + 0) * 68 + nl] = a0.x; As[(c4 + 1) * 68 + nl] = a0.y;                   \
    As[(c4 + 2) * 68 + nl] = a0.z; As[(c4 + 3) * 68 + nl] = a0.w;                   \
    Bs[(c4 + 0) * 68 + nl] = b0.x; Bs[(c4 + 1) * 68 + nl] = b0.y;                   \
    Bs[(c4 + 2) * 68 + nl] = b0.z; Bs[(c4 + 3) * 68 + nl] = b0.w;                   \
    __syncthreads();                                                                \
    _Pragma("unroll") for (int kk = 0; kk < 32; ++kk) {                             \
      float2 av = *(const float2*)(As + kk * 68 + ty * 2);                          \
      float4 bv = *(const float4*)(Bs + kk * 68 + tx * 4);                          \
      acc[0][0] = fmaf(av.x, bv.x, acc[0][0]);                                      \
      acc[0][1] = fmaf(av.x, bv.y, acc[0][1]);                                      \
      acc[0][2] = fmaf(av.x, bv.z, acc[0][2]);                                      \
      acc[0][3] = fmaf(av.x, bv.w, acc[0][3]);                                      \
      acc[1][0] = fmaf(av.y, bv.x, acc[1][0]);                                      \
      acc[1][1] = fmaf(av.y, bv.y, acc[1][1]);                                      \
      acc[1][2] = fmaf(av.y, bv.z, acc[1][2]);                                      \
      acc[1][3] = fmaf(av.y, bv.w, acc[1][3]);                                      \
    }                                                                               \
  }

// ---------------- LSTM GEMM (+ cell epilogue) ----------------
template <int MODE>
__global__ __launch_bounds__(512) void gemm_kernel(
    const float* __restrict__ A, const float* __restrict__ B0,
    const float* __restrict__ bias0, const float* __restrict__ bias1,
    float* __restrict__ out0, float* __restrict__ out1,
    const float* __restrict__ x, const float* __restrict__ F,
    const int* __restrict__ chosen, int t) {
  __shared__ float smem[64 * 68];
  float* As = smem;
  float* Bs = smem + 32 * 68;
  const int tid = threadIdx.x;
  const int tx = tid & 15;        // col group *4
  const int ty = tid >> 4;        // row group *2 (0..31)
  const int m0 = blockIdx.x * 64;
  const int nl = tid >> 3;        // staging row 0..63
  const int c4 = (tid & 7) * 4;   // staging k offset

  const int j = ((nl >> 4) << 8) + (blockIdx.y << 4) + (nl & 15);
  const float* brow = B0 + (size_t)j * 256 + c4;
  const float* ap = A + (size_t)(m0 + nl) * 256 + c4;

  GEMM_LOAD_COMPUTE()

  float bsum[4], fa[4], fb[4];
#pragma unroll
  for (int c = 0; c < 4; ++c) {
    int n = tx * 4 + c;
    int jx = ((n >> 4) << 8) + (blockIdx.y << 4) + (n & 15);
    bsum[c] = bias0[jx] + bias1[jx];
    fa[c] = F[jx];
    if constexpr (MODE != M_DEC0) fb[c] = F[1024 + jx]; else fb[c] = 0.0f;
  }
  float xv0[2] = {0, 0}, xv1[2] = {0, 0};
  if constexpr (MODE == M_ENC) {
#pragma unroll
    for (int r = 0; r < 2; ++r) {
      int m = m0 + ty * 2 + r;
      xv0[r] = x[m * (NS * 2) + t * 2 + 0];
      xv1[r] = x[m * (NS * 2) + t * 2 + 1];
    }
  } else if constexpr (MODE == M_DEC) {
#pragma unroll
    for (int r = 0; r < 2; ++r) {
      int m = m0 + ty * 2 + r;
      int cs = chosen[m];
      xv0[r] = x[m * (NS * 2) + cs * 2 + 0];
      xv1[r] = x[m * (NS * 2) + cs * 2 + 1];
    }
  }
  __syncthreads();
  float* Cs = smem;  // [64][68]
#pragma unroll
  for (int r = 0; r < 2; ++r) {
#pragma unroll
    for (int c = 0; c < 4; ++c) {
      float v = acc[r][c] + bsum[c];
      if constexpr (MODE == M_DEC0) v += fa[c];
      else v += xv0[r] * fa[c] + xv1[r] * fb[c];
      Cs[(ty * 2 + r) * 68 + tx * 4 + c] = v;
    }
  }
  __syncthreads();
  const int b_l = tid >> 3;       // 0..63
  const int h2 = (tid & 7) * 2;   // 0..14
  const float* crow = Cs + b_l * 68;
  float2 gi = *(const float2*)(crow + h2);
  float2 gf = *(const float2*)(crow + 16 + h2);
  float2 gg = *(const float2*)(crow + 32 + h2);
  float2 go = *(const float2*)(crow + 48 + h2);
  size_t base = (size_t)(m0 + b_l) * 256 + (blockIdx.y << 4) + h2;
  float2 cp = *(const float2*)(out1 + base);
  float2 cn, hn;
  cn.x = sigm(gf.x) * cp.x + sigm(gi.x) * tanhf(gg.x); hn.x = sigm(go.x) * tanhf(cn.x);
  cn.y = sigm(gf.y) * cp.y + sigm(gi.y) * tanhf(gg.y); hn.y = sigm(go.y) * tanhf(cn.y);
  *(float2*)(out1 + base) = cn;
  *(float2*)(out0 + base) = hn;
}

// ---------------- keys GEMM, z-batched over 4 steps ----------------
__global__ __launch_bounds__(512) void keys_kernel(
    const float* __restrict__ h0, const float* __restrict__ h1,
    const float* __restrict__ h2p, const float* __restrict__ h3,
    const float* __restrict__ gW, const float* __restrict__ pW,
    const float* __restrict__ gB, const float* __restrict__ pB,
    float* gkf, ushort_t* gkh, ushort_t* gkl,
    float* pkf, ushort_t* pkh, ushort_t* pkl,
    int t0, int nfg, int nqg, int nfp, int nqp) {
  __shared__ float smem[64 * 68];
  float* As = smem;
  float* Bs = smem + 32 * 68;
  const int tid = threadIdx.x;
  const int tx = tid & 15, ty = tid >> 4;
  const int m0 = blockIdx.x * 64;
  const int nl = tid >> 3;
  const int c4 = (tid & 7) * 4;
  const int zz = blockIdx.z;
  const int t = t0 + zz;
  const float* A = (zz == 0) ? h0 : (zz == 1) ? h1 : (zz == 2) ? h2p : h3;

  const int j = blockIdx.y * 64 + nl;   // 0..511
  const float* brow = ((j < 256) ? (gW + (size_t)j * 256) : (pW + (size_t)(j - 256) * 256)) + c4;
  const float* ap = A + (size_t)(m0 + nl) * 256 + c4;

  GEMM_LOAD_COMPUTE()

  const int nbase = blockIdx.y * 64 + tx * 4;
  const bool isp = (nbase >= 256);
  const int n = isp ? (nbase - 256) : nbase;
  float4 b4 = *(const float4*)((isp ? pB : gB) + n);
  float* kf = isp ? pkf : gkf;
  ushort_t* kh = isp ? pkh : gkh;
  ushort_t* kl = isp ? pkl : gkl;
  const int nf = isp ? nfp : nfg;
  const int nq = isp ? nqp : nqg;
#pragma unroll
  for (int r = 0; r < 2; ++r) {
    int m = m0 + ty * 2 + r;
    float4 o;
    o.x = acc[r][0] + b4.x; o.y = acc[r][1] + b4.y;
    o.z = acc[r][2] + b4.z; o.w = acc[r][3] + b4.w;
    if (t < nf) {
      *(float4*)(kf + ((size_t)m * nf + t) * 256 + n) = o;
    } else {
      size_t qb = (size_t)m * nq + (t - nf);
      ushort4 hi; ushort_t u0, u1, u2;
      pack12(o, hi, u0, u1, u2);
      *(ushort4*)(kh + qb * 256 + n) = hi;
      ushort_t* lp = kl + qb * 192 + 3 * (n >> 2);
      lp[0] = u0; lp[1] = u1; lp[2] = u2;
    }
  }
}

// ---------------- fused decoder attention: qproj_g + glimpse + qproj_p + pointer + sample ----------------
__global__ __launch_bounds__(256) void attn_kernel(
    const float* __restrict__ h, const float* __restrict__ gWT, const float* __restrict__ pWT,
    const float* __restrict__ gqb, const float* __restrict__ pqb,
    const float* gkf, const ushort_t* gkh, const ushort_t* gkl, int nfg, int nqg,
    const float* pkf, const ushort_t* pkh, const ushort_t* pkl, int nfp, int nqp,
    const float* __restrict__ gvw, const float* __restrict__ gvb,
    const float* __restrict__ pvw, const float* __restrict__ pvb,
    int* __restrict__ mask, const uint2* __restrict__ skeys, int t,
    float* __restrict__ out, int* __restrict__ chosen_buf) {
  __shared__ float hs[256], qs[256], vs[256], qq[256];
  __shared__ float part[4][256];
  __shared__ float wm[4], wl[4];
  __shared__ float lgs[NS], sv[NS];
  __shared__ int msk[NS];
  __shared__ float red_lse;
  __shared__ int ich;
  const int tid = threadIdx.x;
  const int b = blockIdx.x;
  const int wave = tid >> 6, lane = tid & 63;
  const int h0 = lane * 4;

  hs[tid] = h[b * 256 + tid];
  vs[tid] = gvw[tid];
  if (tid < NS) msk[tid] = mask[b * NS + tid];
  __syncthreads();

  // ---- phase 1: qg = g_Wq . h + b (transposed weights; lane-coalesced) ----
  {
    float a = gqb[tid];
    const float* wc = gWT + tid;
#pragma unroll 8
    for (int k = 0; k < 256; ++k) a = fmaf(wc[(size_t)k * 256], hs[k], a);
    qs[tid] = a;
  }
  __syncthreads();

  // ---- phase 2: glimpse online-softmax attention over g_keys ----
  {
    const size_t bf = (size_t)b * nfg * 256;
    const size_t bq = (size_t)b * nqg;
    const float vbias = gvb[0];
    float q0 = qs[h0], q1 = qs[h0 + 1], q2 = qs[h0 + 2], q3 = qs[h0 + 3];
    float v0 = vs[h0], v1 = vs[h0 + 1], v2 = vs[h0 + 2], v3 = vs[h0 + 3];
    float m = -INFINITY, l = 0.f;
    float4 acc = make_float4(0.f, 0.f, 0.f, 0.f);
    for (int si = 0; si < 32; ++si) {
      int s = wave * 32 + si;
      float4 kv = key_load(gkf, gkh, gkl, bf, bq, s, nfg, h0);
      float p = fast_tanh(q0 + kv.x) * v0 + fast_tanh(q1 + kv.y) * v1 +
                fast_tanh(q2 + kv.z) * v2 + fast_tanh(q3 + kv.w) * v3;
#pragma unroll
      for (int off = 32; off; off >>= 1) p += __shfl_xor(p, off);
      if (!msk[s]) {
        float lg = 10.0f * tanhf(p + vbias);
        float mn = fmaxf(m, lg);
        float scale = (m == -INFINITY) ? 0.0f : expf(m - mn);
        float pe = expf(lg - mn);
        acc.x = fmaf(acc.x, scale, pe * kv.x);
        acc.y = fmaf(acc.y, scale, pe * kv.y);
        acc.z = fmaf(acc.z, scale, pe * kv.z);
        acc.w = fmaf(acc.w, scale, pe * kv.w);
        l = l * scale + pe;
        m = mn;
      }
    }
    *(float4*)&part[wave][h0] = acc;
    if (lane == 0) { wm[wave] = m; wl[wave] = l; }
  }
  __syncthreads();
  {
    float mg = fmaxf(fmaxf(wm[0], wm[1]), fmaxf(wm[2], wm[3]));
    float w0 = (wm[0] == -INFINITY) ? 0.f : expf(wm[0] - mg);
    float w1 = (wm[1] == -INFINITY) ? 0.f : expf(wm[1] - mg);
    float w2 = (wm[2] == -INFINITY) ? 0.f : expf(wm[2] - mg);
    float w3 = (wm[3] == -INFINITY) ? 0.f : expf(wm[3] - mg);
    float denom = w0 * wl[0] + w1 * wl[1] + w2 * wl[2] + w3 * wl[3];
    float num = w0 * part[0][tid] + w1 * part[1][tid] + w2 * part[2][tid] + w3 * part[3][tid];
    qq[tid] = num / denom;
    vs[tid] = pvw[tid];
  }
  __syncthreads();

  // ---- phase 3: qp = p_Wq . query + b ----
  {
    float a = pqb[tid];
    const float* wc = pWT + tid;
#pragma unroll 8
    for (int k = 0; k < 256; ++k) a = fmaf(wc[(size_t)k * 256], qq[k], a);
    qs[tid] = a;
  }
  __syncthreads();

  // ---- phase 4: pointer logits + lse + gumbel sample ----
  {
    const size_t bf = (size_t)b * nfp * 256;
    const size_t bq = (size_t)b * nqp;
    const float vbias = pvb[0];
    float q0 = qs[h0], q1 = qs[h0 + 1], q2 = qs[h0 + 2], q3 = qs[h0 + 3];
    float v0 = vs[h0], v1 = vs[h0 + 1], v2 = vs[h0 + 2], v3 = vs[h0 + 3];
    for (int si = 0; si < 32; ++si) {
      int s = wave * 32 + si;
      float4 kv = key_load(pkf, pkh, pkl, bf, bq, s, nfp, h0);
      float p = fast_tanh(q0 + kv.x) * v0 + fast_tanh(q1 + kv.y) * v1 +
                fast_tanh(q2 + kv.z) * v2 + fast_tanh(q3 + kv.w) * v3;
#pragma unroll
      for (int off = 32; off; off >>= 1) p += __shfl_down(p, off);
      if (lane == 0) {
        float lv = 10.0f * tanhf(p + vbias);
        lgs[s] = msk[s] ? -100000.0f : lv;
      }
    }
  }
  __syncthreads();
  if (wave == 0) {
    float a0 = lgs[lane], a1 = lgs[lane + 64];
    float m = fmaxf(a0, a1);
#pragma unroll
    for (int off = 32; off; off >>= 1) m = fmaxf(m, __shfl_xor(m, off));
    float e0 = expf(a0 - m), e1 = expf(a1 - m);
    float sum = e0 + e1;
#pragma unroll
    for (int off = 32; off; off >>= 1) sum += __shfl_xor(sum, off);
    if (lane == 0) red_lse = m + logf(sum);
  }
  __syncthreads();
  if (tid < NS) {
    uint32_t i = (uint32_t)(b * NS + tid);
    uint2 sk = skeys[t];
    uint32_t o0, o1;
    tf2x32(sk.x, sk.y, 0u, i, o0, o1);
    uint32_t bits = o0 ^ o1;
    float u = __uint_as_float((bits >> 9) | 0x3f800000u) - 1.0f;
    u = u + 1.17549435e-38f;
    u = fmaxf(u, 1.17549435e-38f);
    float g = -logf(-logf(u));
    sv[tid] = lgs[tid] + g;
  }
  __syncthreads();
  if (wave == 0) {
    float bv = sv[lane]; int bi = lane;
    float ov0 = sv[lane + 64];
    if (ov0 > bv) { bv = ov0; bi = lane + 64; }
#pragma unroll
    for (int off = 32; off; off >>= 1) {
      float ov = __shfl_down(bv, off);
      int oi = __shfl_down(bi, off);
      if (ov > bv) { bv = ov; bi = oi; }
    }
    if (lane == 0) ich = bi;
  }
  __syncthreads();
  if (tid == 0) {
    int cs = ich;
    out[b * NS + t] = lgs[cs] - red_lse;
    out[NB * NS + b * NS + t] = (float)cs;
    mask[b * NS + cs] = 1;
    chosen_buf[b] = cs;
  }
}

extern "C" void kernel_launch(void* const* d_in, const int* in_sizes, int n_in,
                              void* d_out, int out_size, void* d_ws, size_t ws_size,
                              hipStream_t stream) {
  const float* x        = (const float*)d_in[0];
  const float* emb_W    = (const float*)d_in[1];
  const float* enc_W_ih = (const float*)d_in[2];
  const float* enc_W_hh = (const float*)d_in[3];
  const float* enc_b_ih = (const float*)d_in[4];
  const float* enc_b_hh = (const float*)d_in[5];
  const float* dec_W_ih = (const float*)d_in[6];
  const float* dec_W_hh = (const float*)d_in[7];
  const float* dec_b_ih = (const float*)d_in[8];
  const float* dec_b_hh = (const float*)d_in[9];
  const float* g_Wq_w = (const float*)d_in[10];
  const float* g_Wq_b = (const float*)d_in[11];
  const float* g_Wk_w = (const float*)d_in[12];
  const float* g_Wk_b = (const float*)d_in[13];
  const float* g_v_w  = (const float*)d_in[14];
  const float* g_v_b  = (const float*)d_in[15];
  const float* p_Wq_w = (const float*)d_in[16];
  const float* p_Wq_b = (const float*)d_in[17];
  const float* p_Wk_w = (const float*)d_in[18];
  const float* p_Wk_b = (const float*)d_in[19];
  const float* p_v_w  = (const float*)d_in[20];
  const float* p_v_b  = (const float*)d_in[21];
  const float* dec_start = (const float*)d_in[22];
  (void)in_sizes; (void)n_in;

  // ---- per-slot key precision plan (fp32 + 3.5-byte tail), sized from ws_size ----
  const size_t SLOT_F = (size_t)NB * NH * 4;    // 1 MiB
  const size_t SLOT_H = (size_t)NB * NH * 2;    // 512 KiB
  const size_t SLOT_L = (size_t)NB * 192 * 2;   // 384 KiB
  const size_t FULLK = 256 * SLOT_F;
  const size_t EX = 8 * 1048576;
  long long deficit = (long long)(FULLK + EX) - (long long)ws_size;
  int nq_total = (deficit <= 0) ? 0 : (int)((deficit + 131071) / 131072);
  if (nq_total > 256) {
    diag_fill<<<(out_size + 255) / 256, 256, 0, stream>>>((float*)d_out, (float)ws_size, out_size);
    return;
  }
  const int nq_p = nq_total < 128 ? nq_total : 128;
  const int nq_g = nq_total - nq_p;
  const int nf_p = 128 - nq_p;
  const int nf_g = 128 - nq_g;

  char* w = (char*)d_ws;
  size_t off = 0;
  auto alloc = [&](size_t bytes) -> void* {
    void* p = w + off;
    off += (bytes + 255) & ~(size_t)255;
    return p;
  };
  float*    gkf = (float*)alloc((size_t)nf_g * SLOT_F);
  ushort_t* gkh = (ushort_t*)alloc((size_t)nq_g * SLOT_H);
  ushort_t* gkl = (ushort_t*)alloc((size_t)nq_g * SLOT_L);
  float*    pkf = (float*)alloc((size_t)nf_p * SLOT_F);
  ushort_t* pkh = (ushort_t*)alloc((size_t)nq_p * SLOT_H);
  ushort_t* pkl = (ushort_t*)alloc((size_t)nq_p * SLOT_L);

  float* hb[4];
  for (int i = 0; i < 4; ++i) hb[i] = (float*)alloc((size_t)NB * NH * 4);
  float* zbuf   = (float*)alloc((size_t)NB * NH * 4);
  float* cbuf   = (float*)alloc((size_t)NB * NH * 4);
  int*   mask   = (int*)alloc((size_t)NB * NS * 4);
  int*   chosen = (int*)alloc((size_t)NB * 4);
  float* F_enc  = (float*)alloc(2048 * 4);
  float* F_dec  = (float*)alloc(2048 * 4);
  float* d0proj = (float*)alloc(1024 * 4);
  uint2* skeys  = (uint2*)alloc(NS * 8);
  float* gWT    = (float*)alloc(256 * 256 * 4);
  float* pWT    = (float*)alloc(256 * 256 * 4);

  if (off > ws_size) {
    diag_fill<<<(out_size + 255) / 256, 256, 0, stream>>>((float*)d_out, (float)ws_size, out_size);
    return;
  }

  hipMemsetAsync(zbuf, 0, (size_t)NB * NH * 4, stream);
  hipMemsetAsync(cbuf, 0, (size_t)NB * NH * 4, stream);
  hipMemsetAsync(mask, 0, (size_t)NB * NS * 4, stream);
  prep_kernel<<<4, 256, 0, stream>>>(emb_W, enc_W_ih, dec_W_ih, dec_start,
                                     F_enc, F_dec, d0proj, skeys);
  transpose_qw<<<256, 256, 0, stream>>>(g_Wq_w, p_Wq_w, gWT, pWT);

  // ---- encoder: LSTM each step; keys batched every 4 steps ----
  for (int t = 0; t < NS; ++t) {
    const float* hin = (t == 0) ? zbuf : hb[(t - 1) & 3];
    gemm_kernel<M_ENC><<<dim3(16, 16), 512, 0, stream>>>(
        hin, enc_W_hh, enc_b_ih, enc_b_hh, hb[t & 3], cbuf, x, F_enc, nullptr, t);
    if ((t & 3) == 3) {
      keys_kernel<<<dim3(16, 8, 4), 512, 0, stream>>>(
          hb[0], hb[1], hb[2], hb[3], g_Wk_w, p_Wk_w, g_Wk_b, p_Wk_b,
          gkf, gkh, gkl, pkf, pkh, pkl, t - 3, nf_g, nq_g, nf_p, nq_p);
    }
  }
  // ---- decoder: LSTM + fused attention/sample per step ----
  for (int t = 0; t < NS; ++t) {
    const float* hin = (t == 0) ? hb[3] : hb[(t - 1) & 3];
    if (t == 0) {
      gemm_kernel<M_DEC0><<<dim3(16, 16), 512, 0, stream>>>(
          hin, dec_W_hh, dec_b_ih, dec_b_hh, hb[0], cbuf, nullptr, d0proj, nullptr, t);
    } else {
      gemm_kernel<M_DEC><<<dim3(16, 16), 512, 0, stream>>>(
          hin, dec_W_hh, dec_b_ih, dec_b_hh, hb[t & 3], cbuf, x, F_dec, chosen, t);
    }
    attn_kernel<<<NB, 256, 0, stream>>>(
        hb[t & 3], gWT, pWT, g_Wq_b, p_Wq_b,
        gkf, gkh, gkl, nf_g, nq_g, pkf, pkh, pkl, nf_p, nq_p,
        g_v_w, g_v_b, p_v_w, p_v_b, mask, skeys, t, (float*)d_out, chosen);
  }
}

// Round 5
// 16358.157 us; speedup vs baseline: 1.1861x; 1.0164x over previous
//
#include <hip/hip_runtime.h>
#include <cstdint>

#define NB 1024
#define NS 128
#define NE 256
#define NH 256

#define M_ENC 0
#define M_DEC0 1
#define M_DEC 2

typedef unsigned short ushort_t;
typedef unsigned char uchar_t;

__device__ __forceinline__ void tf2x32(uint32_t k0, uint32_t k1, uint32_t x0, uint32_t x1,
                                       uint32_t &o0, uint32_t &o1) {
  const uint32_t ks2 = k0 ^ k1 ^ 0x1BD11BDAu;
#define TF_R(r) { x0 += x1; x1 = (x1 << (r)) | (x1 >> (32 - (r))); x1 ^= x0; }
  x0 += k0; x1 += k1;
  TF_R(13) TF_R(15) TF_R(26) TF_R(6)
  x0 += k1; x1 += ks2 + 1u;
  TF_R(17) TF_R(29) TF_R(16) TF_R(24)
  x0 += ks2; x1 += k0 + 2u;
  TF_R(13) TF_R(15) TF_R(26) TF_R(6)
  x0 += k0; x1 += k1 + 3u;
  TF_R(17) TF_R(29) TF_R(16) TF_R(24)
  x0 += k1; x1 += ks2 + 4u;
  TF_R(13) TF_R(15) TF_R(26) TF_R(6)
  x0 += ks2; x1 += k0 + 5u;
#undef TF_R
  o0 = x0; o1 = x1;
}

__device__ __forceinline__ float fast_tanh(float x) {
  float ax = fabsf(x);
  float e = __expf(2.0f * ax);
  float r = 1.0f - 2.0f / (e + 1.0f);
  return copysignf(r, x);
}

__device__ __forceinline__ float sigm(float x) { return 1.0f / (1.0f + expf(-x)); }

// ---- 3.5-byte key codec: keep fp32 bits [31:4] with RTN. Arrays: hi16, lo8, nibble4 ----
__device__ __forceinline__ void pack28(float4 o, ushort4 &hi, uchar4 &l8, ushort_t &nib) {
  uint32_t a = __float_as_uint(o.x) + 8u;
  uint32_t b = __float_as_uint(o.y) + 8u;
  uint32_t c = __float_as_uint(o.z) + 8u;
  uint32_t d = __float_as_uint(o.w) + 8u;
  hi = make_ushort4((ushort_t)(a >> 16), (ushort_t)(b >> 16), (ushort_t)(c >> 16), (ushort_t)(d >> 16));
  l8 = make_uchar4((uchar_t)(a >> 8), (uchar_t)(b >> 8), (uchar_t)(c >> 8), (uchar_t)(d >> 8));
  nib = (ushort_t)(((a >> 4) & 0xFu) | (((b >> 4) & 0xFu) << 4) |
                   (((c >> 4) & 0xFu) << 8) | (((d >> 4) & 0xFu) << 12));
}

// row = b*NS + slot; h0 = lane*4
__device__ __forceinline__ float4 key_load(const ushort_t* __restrict__ kh,
                                           const uchar_t* __restrict__ k8,
                                           const ushort_t* __restrict__ kn,
                                           size_t row, int h0) {
  ushort4 hv = *(const ushort4*)(kh + row * 256 + h0);
  uchar4 lv = *(const uchar4*)(k8 + row * 256 + h0);
  uint32_t nv = kn[row * 64 + (h0 >> 2)];
  float4 r;
  r.x = __uint_as_float(((uint32_t)hv.x << 16) | ((uint32_t)lv.x << 8) | ((nv & 0xFu) << 4));
  r.y = __uint_as_float(((uint32_t)hv.y << 16) | ((uint32_t)lv.y << 8) | (((nv >> 4) & 0xFu) << 4));
  r.z = __uint_as_float(((uint32_t)hv.z << 16) | ((uint32_t)lv.z << 8) | (((nv >> 8) & 0xFu) << 4));
  r.w = __uint_as_float(((uint32_t)hv.w << 16) | ((uint32_t)lv.w << 8) | (((nv >> 12) & 0xFu) << 4));
  return r;
}

// ---------------- prep: fold emb_W through input weights; threefry split keys ----------------
__global__ __launch_bounds__(256) void prep_kernel(
    const float* __restrict__ emb_W, const float* __restrict__ enc_W_ih,
    const float* __restrict__ dec_W_ih, const float* __restrict__ dec_start,
    float* __restrict__ F_enc, float* __restrict__ F_dec,
    float* __restrict__ d0proj, uint2* __restrict__ skeys) {
  int j = blockIdx.x * 256 + threadIdx.x;  // 0..1023
  const float* er = enc_W_ih + j * 256;
  const float* dr = dec_W_ih + j * 256;
  float fe0 = 0.f, fe1 = 0.f, fd0 = 0.f, fd1 = 0.f, dp = 0.f;
  for (int e = 0; e < 256; ++e) {
    float we0 = emb_W[e], we1 = emb_W[256 + e];
    float ev = er[e], dv = dr[e];
    fe0 = fmaf(we0, ev, fe0); fe1 = fmaf(we1, ev, fe1);
    fd0 = fmaf(we0, dv, fd0); fd1 = fmaf(we1, dv, fd1);
    dp = fmaf(dec_start[e], dv, dp);
  }
  F_enc[j] = fe0; F_enc[1024 + j] = fe1;
  F_dec[j] = fd0; F_dec[1024 + j] = fd1;
  d0proj[j] = dp;
  if (blockIdx.x == 0 && threadIdx.x < NS) {
    uint32_t o0, o1;
    tf2x32(0u, 42u, 0u, (uint32_t)threadIdx.x, o0, o1);
    skeys[threadIdx.x] = make_uint2(o0, o1);
  }
}

// transpose the two query-projection weights: WT[k][j] = W[j][k]
__global__ __launch_bounds__(256) void transpose_qw(
    const float* __restrict__ gW, const float* __restrict__ pW,
    float* __restrict__ gWT, float* __restrict__ pWT) {
  int k = blockIdx.x, j = threadIdx.x;
  gWT[k * 256 + j] = gW[j * 256 + k];
  pWT[k * 256 + j] = pW[j * 256 + k];
}

__global__ void diag_fill(float* out, float v, int n) {
  int i = blockIdx.x * blockDim.x + threadIdx.x;
  if (i < n) out[i] = v;
}

// ---------------- GEMM macro body: 512 threads, 64x64 tile, K=256, acc[2][4] ----------------
#define GEMM_LOAD_COMPUTE()                                                         \
  float acc[2][4];                                                                  \
  _Pragma("unroll") for (int i = 0; i < 2; ++i)                                     \
      _Pragma("unroll") for (int jj = 0; jj < 4; ++jj) acc[i][jj] = 0.0f;           \
  for (int k0 = 0; k0 < 256; k0 += 32) {                                            \
    float4 a0 = *(const float4*)(ap + k0);                                          \
    float4 b0 = *(const float4*)(brow + k0);                                        \
    __syncthreads();                                                                \
    As[(c4 + 0) * 68 + nl] = a0.x; As[(c4 + 1) * 68 + nl] = a0.y;                   \
    As[(c4 + 2) * 68 + nl] = a0.z; As[(c4 + 3) * 68 + nl] = a0.w;                   \
    Bs[(c4 + 0) * 68 + nl] = b0.x; Bs[(c4 + 1) * 68 + nl] = b0.y;                   \
    Bs[(c4 + 2) * 68 + nl] = b0.z; Bs[(c4 + 3) * 68 + nl] = b0.w;                   \
    __syncthreads();                                                                \
    _Pragma("unroll") for (int kk = 0; kk < 32; ++kk) {                             \
      float2 av = *(const float2*)(As + kk * 68 + ty * 2);                          \
      float4 bv = *(const float4*)(Bs + kk * 68 + tx * 4);                          \
      acc[0][0] = fmaf(av.x, bv.x, acc[0][0]);                                      \
      acc[0][1] = fmaf(av.x, bv.y, acc[0][1]);                                      \
      acc[0][2] = fmaf(av.x, bv.z, acc[0][2]);                                      \
      acc[0][3] = fmaf(av.x, bv.w, acc[0][3]);                                      \
      acc[1][0] = fmaf(av.y, bv.x, acc[1][0]);                                      \
      acc[1][1] = fmaf(av.y, bv.y, acc[1][1]);                                      \
      acc[1][2] = fmaf(av.y, bv.z, acc[1][2]);                                      \
      acc[1][3] = fmaf(av.y, bv.w, acc[1][3]);                                      \
    }                                                                               \
  }

// ---------------- LSTM GEMM (+ cell epilogue) ----------------
template <int MODE>
__global__ __launch_bounds__(512) void gemm_kernel(
    const float* __restrict__ A, const float* __restrict__ B0,
    const float* __restrict__ bias0, const float* __restrict__ bias1,
    float* __restrict__ out0, float* __restrict__ out1,
    const float* __restrict__ x, const float* __restrict__ F,
    const int* __restrict__ chosen, int t) {
  __shared__ float smem[64 * 68];
  float* As = smem;
  float* Bs = smem + 32 * 68;
  const int tid = threadIdx.x;
  const int tx = tid & 15;
  const int ty = tid >> 4;
  const int m0 = blockIdx.x * 64;
  const int nl = tid >> 3;
  const int c4 = (tid & 7) * 4;

  const int j = ((nl >> 4) << 8) + (blockIdx.y << 4) + (nl & 15);
  const float* brow = B0 + (size_t)j * 256 + c4;
  const float* ap = A + (size_t)(m0 + nl) * 256 + c4;

  GEMM_LOAD_COMPUTE()

  float bsum[4], fa[4], fb[4];
#pragma unroll
  for (int c = 0; c < 4; ++c) {
    int n = tx * 4 + c;
    int jx = ((n >> 4) << 8) + (blockIdx.y << 4) + (n & 15);
    bsum[c] = bias0[jx] + bias1[jx];
    fa[c] = F[jx];
    if constexpr (MODE != M_DEC0) fb[c] = F[1024 + jx]; else fb[c] = 0.0f;
  }
  float xv0[2] = {0, 0}, xv1[2] = {0, 0};
  if constexpr (MODE == M_ENC) {
#pragma unroll
    for (int r = 0; r < 2; ++r) {
      int m = m0 + ty * 2 + r;
      xv0[r] = x[m * (NS * 2) + t * 2 + 0];
      xv1[r] = x[m * (NS * 2) + t * 2 + 1];
    }
  } else if constexpr (MODE == M_DEC) {
#pragma unroll
    for (int r = 0; r < 2; ++r) {
      int m = m0 + ty * 2 + r;
      int cs = chosen[m];
      xv0[r] = x[m * (NS * 2) + cs * 2 + 0];
      xv1[r] = x[m * (NS * 2) + cs * 2 + 1];
    }
  }
  __syncthreads();
  float* Cs = smem;  // [64][68]
#pragma unroll
  for (int r = 0; r < 2; ++r) {
#pragma unroll
    for (int c = 0; c < 4; ++c) {
      float v = acc[r][c] + bsum[c];
      if constexpr (MODE == M_DEC0) v += fa[c];
      else v += xv0[r] * fa[c] + xv1[r] * fb[c];
      Cs[(ty * 2 + r) * 68 + tx * 4 + c] = v;
    }
  }
  __syncthreads();
  const int b_l = tid >> 3;
  const int h2 = (tid & 7) * 2;
  const float* crow = Cs + b_l * 68;
  float2 gi = *(const float2*)(crow + h2);
  float2 gf = *(const float2*)(crow + 16 + h2);
  float2 gg = *(const float2*)(crow + 32 + h2);
  float2 go = *(const float2*)(crow + 48 + h2);
  size_t base = (size_t)(m0 + b_l) * 256 + (blockIdx.y << 4) + h2;
  float2 cp = *(const float2*)(out1 + base);
  float2 cn, hn;
  cn.x = sigm(gf.x) * cp.x + sigm(gi.x) * tanhf(gg.x); hn.x = sigm(go.x) * tanhf(cn.x);
  cn.y = sigm(gf.y) * cp.y + sigm(gi.y) * tanhf(gg.y); hn.y = sigm(go.y) * tanhf(cn.y);
  *(float2*)(out1 + base) = cn;
  *(float2*)(out0 + base) = hn;
}

// ---------------- keys GEMM, z-batched over 4 steps, quantized stores ----------------
__global__ __launch_bounds__(512) void keys_kernel(
    const float* __restrict__ hbase,
    const float* __restrict__ gW, const float* __restrict__ pW,
    const float* __restrict__ gB, const float* __restrict__ pB,
    ushort_t* gkh, uchar_t* gk8, ushort_t* gkn,
    ushort_t* pkh, uchar_t* pk8, ushort_t* pkn, int t0) {
  __shared__ float smem[64 * 68];
  float* As = smem;
  float* Bs = smem + 32 * 68;
  const int tid = threadIdx.x;
  const int tx = tid & 15, ty = tid >> 4;
  const int m0 = blockIdx.x * 64;
  const int nl = tid >> 3;
  const int c4 = (tid & 7) * 4;
  const int zz = blockIdx.z;
  const int t = t0 + zz;
  const float* A = hbase + (size_t)zz * NB * NH;

  const int j = blockIdx.y * 64 + nl;   // 0..511
  const float* brow = ((j < 256) ? (gW + (size_t)j * 256) : (pW + (size_t)(j - 256) * 256)) + c4;
  const float* ap = A + (size_t)(m0 + nl) * 256 + c4;

  GEMM_LOAD_COMPUTE()

  const int nbase = blockIdx.y * 64 + tx * 4;
  const bool isp = (nbase >= 256);
  const int n = isp ? (nbase - 256) : nbase;
  float4 b4 = *(const float4*)((isp ? pB : gB) + n);
  ushort_t* kh = isp ? pkh : gkh;
  uchar_t* k8 = isp ? pk8 : gk8;
  ushort_t* kn = isp ? pkn : gkn;
#pragma unroll
  for (int r = 0; r < 2; ++r) {
    int m = m0 + ty * 2 + r;
    float4 o;
    o.x = acc[r][0] + b4.x; o.y = acc[r][1] + b4.y;
    o.z = acc[r][2] + b4.z; o.w = acc[r][3] + b4.w;
    size_t row = (size_t)m * NS + t;
    ushort4 hi; uchar4 l8; ushort_t nib;
    pack28(o, hi, l8, nib);
    *(ushort4*)(kh + row * 256 + n) = hi;
    *(uchar4*)(k8 + row * 256 + n) = l8;
    kn[row * 64 + (n >> 2)] = nib;
  }
}

// ---------------- fused decoder attention: 4 batch rows / block ----------------
__global__ __launch_bounds__(1024, 1) void attn_kernel(
    const float* __restrict__ h, const float* __restrict__ gWT, const float* __restrict__ pWT,
    const float* __restrict__ gqb, const float* __restrict__ pqb,
    const ushort_t* __restrict__ gkh, const uchar_t* __restrict__ gk8, const ushort_t* __restrict__ gkn,
    const ushort_t* __restrict__ pkh, const uchar_t* __restrict__ pk8, const ushort_t* __restrict__ pkn,
    const float* __restrict__ gvw, const float* __restrict__ gvb,
    const float* __restrict__ pvw, const float* __restrict__ pvb,
    int* __restrict__ mask, const uint2* __restrict__ skeys, int t,
    float* __restrict__ out, int* __restrict__ chosen_buf) {
  __shared__ float hs[4][256], qs[4][256], vs[4][256], qq[4][256];
  __shared__ float part[4][4][256];
  __shared__ float wm[4][4], wl[4][4];
  __shared__ float lgs[4][NS], sv[4][NS];
  __shared__ int msk[4][NS];
  __shared__ float red_lse[4];
  __shared__ int ich[4];

  const int tid = threadIdx.x;
  const int grp = tid >> 8;          // 0..3 (4 whole waves each)
  const int gt = tid & 255;          // thread-in-group
  const int b = blockIdx.x * 4 + grp;
  const int wv = gt >> 6, lane = gt & 63;
  const int h0 = lane * 4;

  hs[grp][gt] = h[b * 256 + gt];
  vs[grp][gt] = gvw[gt];
  if (gt < NS) msk[grp][gt] = mask[b * NS + gt];
  __syncthreads();

  // ---- phase 1: qg = g_Wq . h + b ----
  {
    float a = gqb[gt];
    const float* wc = gWT + gt;
#pragma unroll 8
    for (int k = 0; k < 256; ++k) a = fmaf(wc[k * 256], hs[grp][k], a);
    qs[grp][gt] = a;
  }
  __syncthreads();

  // ---- phase 2: glimpse online-softmax attention ----
  {
    const float vbias = gvb[0];
    float q0 = qs[grp][h0], q1 = qs[grp][h0 + 1], q2 = qs[grp][h0 + 2], q3 = qs[grp][h0 + 3];
    float v0 = vs[grp][h0], v1 = vs[grp][h0 + 1], v2 = vs[grp][h0 + 2], v3 = vs[grp][h0 + 3];
    float m = -INFINITY, l = 0.f;
    float4 acc = make_float4(0.f, 0.f, 0.f, 0.f);
#pragma unroll 2
    for (int si = 0; si < 32; ++si) {
      int s = wv * 32 + si;
      size_t row = (size_t)b * NS + s;
      float4 kv = key_load(gkh, gk8, gkn, row, h0);
      float p = fast_tanh(q0 + kv.x) * v0 + fast_tanh(q1 + kv.y) * v1 +
                fast_tanh(q2 + kv.z) * v2 + fast_tanh(q3 + kv.w) * v3;
#pragma unroll
      for (int off = 32; off; off >>= 1) p += __shfl_xor(p, off);
      if (!msk[grp][s]) {
        float lg = 10.0f * tanhf(p + vbias);
        float mn = fmaxf(m, lg);
        float scale = (m == -INFINITY) ? 0.0f : expf(m - mn);
        float pe = expf(lg - mn);
        acc.x = fmaf(acc.x, scale, pe * kv.x);
        acc.y = fmaf(acc.y, scale, pe * kv.y);
        acc.z = fmaf(acc.z, scale, pe * kv.z);
        acc.w = fmaf(acc.w, scale, pe * kv.w);
        l = l * scale + pe;
        m = mn;
      }
    }
    *(float4*)&part[grp][wv][h0] = acc;
    if (lane == 0) { wm[grp][wv] = m; wl[grp][wv] = l; }
  }
  __syncthreads();
  {
    float mg = fmaxf(fmaxf(wm[grp][0], wm[grp][1]), fmaxf(wm[grp][2], wm[grp][3]));
    float w0 = (wm[grp][0] == -INFINITY) ? 0.f : expf(wm[grp][0] - mg);
    float w1 = (wm[grp][1] == -INFINITY) ? 0.f : expf(wm[grp][1] - mg);
    float w2 = (wm[grp][2] == -INFINITY) ? 0.f : expf(wm[grp][2] - mg);
    float w3 = (wm[grp][3] == -INFINITY) ? 0.f : expf(wm[grp][3] - mg);
    float denom = w0 * wl[grp][0] + w1 * wl[grp][1] + w2 * wl[grp][2] + w3 * wl[grp][3];
    float num = w0 * part[grp][0][gt] + w1 * part[grp][1][gt] +
                w2 * part[grp][2][gt] + w3 * part[grp][3][gt];
    qq[grp][gt] = num / denom;
    vs[grp][gt] = pvw[gt];
  }
  __syncthreads();

  // ---- phase 3: qp = p_Wq . query + b ----
  {
    float a = pqb[gt];
    const float* wc = pWT + gt;
#pragma unroll 8
    for (int k = 0; k < 256; ++k) a = fmaf(wc[k * 256], qq[grp][k], a);
    qs[grp][gt] = a;
  }
  __syncthreads();

  // ---- phase 4: pointer logits ----
  {
    const float vbias = pvb[0];
    float q0 = qs[grp][h0], q1 = qs[grp][h0 + 1], q2 = qs[grp][h0 + 2], q3 = qs[grp][h0 + 3];
    float v0 = vs[grp][h0], v1 = vs[grp][h0 + 1], v2 = vs[grp][h0 + 2], v3 = vs[grp][h0 + 3];
#pragma unroll 2
    for (int si = 0; si < 32; ++si) {
      int s = wv * 32 + si;
      size_t row = (size_t)b * NS + s;
      float4 kv = key_load(pkh, pk8, pkn, row, h0);
      float p = fast_tanh(q0 + kv.x) * v0 + fast_tanh(q1 + kv.y) * v1 +
                fast_tanh(q2 + kv.z) * v2 + fast_tanh(q3 + kv.w) * v3;
#pragma unroll
      for (int off = 32; off; off >>= 1) p += __shfl_down(p, off);
      if (lane == 0) {
        float lv = 10.0f * tanhf(p + vbias);
        lgs[grp][s] = msk[grp][s] ? -100000.0f : lv;
      }
    }
  }
  __syncthreads();
  if (wv == 0) {
    float a0 = lgs[grp][lane], a1 = lgs[grp][lane + 64];
    float m = fmaxf(a0, a1);
#pragma unroll
    for (int off = 32; off; off >>= 1) m = fmaxf(m, __shfl_xor(m, off));
    float e0 = expf(a0 - m), e1 = expf(a1 - m);
    float sum = e0 + e1;
#pragma unroll
    for (int off = 32; off; off >>= 1) sum += __shfl_xor(sum, off);
    if (lane == 0) red_lse[grp] = m + logf(sum);
  }
  __syncthreads();
  if (gt < NS) {
    uint32_t i = (uint32_t)(b * NS + gt);
    uint2 sk = skeys[t];
    uint32_t o0, o1;
    tf2x32(sk.x, sk.y, 0u, i, o0, o1);
    uint32_t bits = o0 ^ o1;
    float u = __uint_as_float((bits >> 9) | 0x3f800000u) - 1.0f;
    u = u + 1.17549435e-38f;
    u = fmaxf(u, 1.17549435e-38f);
    float g = -logf(-logf(u));
    sv[grp][gt] = lgs[grp][gt] + g;
  }
  __syncthreads();
  if (wv == 0) {
    float bv = sv[grp][lane]; int bi = lane;
    float ov0 = sv[grp][lane + 64];
    if (ov0 > bv) { bv = ov0; bi = lane + 64; }
#pragma unroll
    for (int off = 32; off; off >>= 1) {
      float ov = __shfl_down(bv, off);
      int oi = __shfl_down(bi, off);
      if (ov > bv) { bv = ov; bi = oi; }
    }
    if (lane == 0) ich[grp] = bi;
  }
  __syncthreads();
  if (gt == 0) {
    int cs = ich[grp];
    out[b * NS + t] = lgs[grp][cs] - red_lse[grp];
    out[NB * NS + b * NS + t] = (float)cs;
    mask[b * NS + cs] = 1;
    chosen_buf[b] = cs;
  }
}

extern "C" void kernel_launch(void* const* d_in, const int* in_sizes, int n_in,
                              void* d_out, int out_size, void* d_ws, size_t ws_size,
                              hipStream_t stream) {
  const float* x        = (const float*)d_in[0];
  const float* emb_W    = (const float*)d_in[1];
  const float* enc_W_ih = (const float*)d_in[2];
  const float* enc_W_hh = (const float*)d_in[3];
  const float* enc_b_ih = (const float*)d_in[4];
  const float* enc_b_hh = (const float*)d_in[5];
  const float* dec_W_ih = (const float*)d_in[6];
  const float* dec_W_hh = (const float*)d_in[7];
  const float* dec_b_ih = (const float*)d_in[8];
  const float* dec_b_hh = (const float*)d_in[9];
  const float* g_Wq_w = (const float*)d_in[10];
  const float* g_Wq_b = (const float*)d_in[11];
  const float* g_Wk_w = (const float*)d_in[12];
  const float* g_Wk_b = (const float*)d_in[13];
  const float* g_v_w  = (const float*)d_in[14];
  const float* g_v_b  = (const float*)d_in[15];
  const float* p_Wq_w = (const float*)d_in[16];
  const float* p_Wq_b = (const float*)d_in[17];
  const float* p_Wk_w = (const float*)d_in[18];
  const float* p_Wk_b = (const float*)d_in[19];
  const float* p_v_w  = (const float*)d_in[20];
  const float* p_v_b  = (const float*)d_in[21];
  const float* dec_start = (const float*)d_in[22];
  (void)in_sizes; (void)n_in;

  const size_t KELEM = (size_t)NB * NS * NH;   // 33.55M per head
  char* w = (char*)d_ws;
  size_t off = 0;
  auto alloc = [&](size_t bytes) -> void* {
    void* p = w + off;
    off += (bytes + 255) & ~(size_t)255;
    return p;
  };
  // quantized keys: 3.5 B/elem, both heads = 224 MiB total (L3-resident)
  ushort_t* gkh = (ushort_t*)alloc(KELEM * 2);
  uchar_t*  gk8 = (uchar_t*)alloc(KELEM);
  ushort_t* gkn = (ushort_t*)alloc(KELEM / 2);
  ushort_t* pkh = (ushort_t*)alloc(KELEM * 2);
  uchar_t*  pk8 = (uchar_t*)alloc(KELEM);
  ushort_t* pkn = (ushort_t*)alloc(KELEM / 2);

  float* hb[4];
  for (int i = 0; i < 4; ++i) hb[i] = (float*)alloc((size_t)NB * NH * 4);
  float* cbuf   = (float*)alloc((size_t)NB * NH * 4);
  int*   mask   = (int*)alloc((size_t)NB * NS * 4);
  int*   chosen = (int*)alloc((size_t)NB * 4);
  float* F_enc  = (float*)alloc(2048 * 4);
  float* F_dec  = (float*)alloc(2048 * 4);
  float* d0proj = (float*)alloc(1024 * 4);
  uint2* skeys  = (uint2*)alloc(NS * 8);
  float* gWT    = (float*)alloc(256 * 256 * 4);
  float* pWT    = (float*)alloc(256 * 256 * 4);

  if (off > ws_size) {
    diag_fill<<<(out_size + 255) / 256, 256, 0, stream>>>((float*)d_out, (float)ws_size, out_size);
    return;
  }

  hipMemsetAsync(hb[3], 0, (size_t)NB * NH * 4, stream);   // zero h_in for encoder t=0
  hipMemsetAsync(cbuf, 0, (size_t)NB * NH * 4, stream);
  hipMemsetAsync(mask, 0, (size_t)NB * NS * 4, stream);
  prep_kernel<<<4, 256, 0, stream>>>(emb_W, enc_W_ih, dec_W_ih, dec_start,
                                     F_enc, F_dec, d0proj, skeys);
  transpose_qw<<<256, 256, 0, stream>>>(g_Wq_w, p_Wq_w, gWT, pWT);

  // ---- encoder: LSTM each step; keys batched every 4 steps ----
  for (int t = 0; t < NS; ++t) {
    const float* hin = (t == 0) ? hb[3] : hb[(t - 1) & 3];
    gemm_kernel<M_ENC><<<dim3(16, 16), 512, 0, stream>>>(
        hin, enc_W_hh, enc_b_ih, enc_b_hh, hb[t & 3], cbuf, x, F_enc, nullptr, t);
    if ((t & 3) == 3) {
      keys_kernel<<<dim3(16, 8, 4), 512, 0, stream>>>(
          hb[0], g_Wk_w, p_Wk_w, g_Wk_b, p_Wk_b,
          gkh, gk8, gkn, pkh, pk8, pkn, t - 3);
    }
  }
  // ---- decoder: LSTM + fused attention/sample per step ----
  for (int t = 0; t < NS; ++t) {
    const float* hin = (t == 0) ? hb[3] : hb[(t - 1) & 3];
    if (t == 0) {
      gemm_kernel<M_DEC0><<<dim3(16, 16), 512, 0, stream>>>(
          hin, dec_W_hh, dec_b_ih, dec_b_hh, hb[0], cbuf, nullptr, d0proj, nullptr, t);
    } else {
      gemm_kernel<M_DEC><<<dim3(16, 16), 512, 0, stream>>>(
          hin, dec_W_hh, dec_b_ih, dec_b_hh, hb[t & 3], cbuf, x, F_dec, chosen, t);
    }
    attn_kernel<<<NB / 4, 1024, 0, stream>>>(
        hb[t & 3], gWT, pWT, g_Wq_b, p_Wq_b,
        gkh, gk8, gkn, pkh, pk8, pkn,
        g_v_w, g_v_b, p_v_w, p_v_b, mask, skeys, t, (float*)d_out, chosen);
  }
}